// Round 1
// baseline (683.487 us; speedup 1.0000x reference)
//
#include <hip/hip_runtime.h>

#define EPSV 1e-5f

__device__ __forceinline__ float wave_red(float v) {
#pragma unroll
  for (int off = 32; off > 0; off >>= 1) v += __shfl_xor(v, off, 64);
  return v;
}

// ---- CSR build ------------------------------------------------------------

__global__ void k_count(const int* __restrict__ dst, int* __restrict__ deg, int E) {
  int e = blockIdx.x * blockDim.x + threadIdx.x;
  if (e < E) atomicAdd(&deg[dst[e]], 1);
}

__global__ __launch_bounds__(1024) void k_scan(const int* __restrict__ deg,
                                               int* __restrict__ row_start,
                                               int* __restrict__ cursor,
                                               float* __restrict__ dinv, int N) {
  __shared__ int sums[1024];
  int tid = threadIdx.x;
  int SEG = (N + 1023) >> 10;
  int s = tid * SEG;
  int epos = min(s + SEG, N);
  int acc = 0;
  for (int i = s; i < epos; i++) acc += deg[i];
  sums[tid] = acc;
  __syncthreads();
  // Hillis-Steele inclusive scan over 1024 partials
  for (int off = 1; off < 1024; off <<= 1) {
    int v = (tid >= off) ? sums[tid - off] : 0;
    __syncthreads();
    sums[tid] += v;
    __syncthreads();
  }
  int run = (tid > 0) ? sums[tid - 1] : 0;
  for (int i = s; i < epos; i++) {
    row_start[i] = run;
    cursor[i] = run;
    run += deg[i];
    // reference: deg includes the self-loop (+1); always > 0
    dinv[i] = rsqrtf((float)(deg[i] + 1));
  }
}

__global__ void k_fill(const int* __restrict__ src, const int* __restrict__ dst,
                       int* __restrict__ cursor, int* __restrict__ csr_src, int E) {
  int e = blockIdx.x * blockDim.x + threadIdx.x;
  if (e < E) {
    int d = dst[e];
    int pos = atomicAdd(&cursor[d], 1);
    csr_src[pos] = src[e];
  }
}

// ---- GEMM: [N x 128] @ [128 x COLS] --------------------------------------
// 256 threads; thread = (cg, rt): cg owns 8 cols, rt owns RPT rows.
// x tile staged in LDS (padded stride 132 to break bank conflicts; 132*4B is
// 16B-multiple so float4 LDS ops stay aligned). W read via L1/L2 (64KB,
// fully cache-resident across blocks).

template <int COLS, int RPT>
__global__ __launch_bounds__(256) void k_gemm(const float* __restrict__ A,
                                              const float* __restrict__ W,
                                              float* __restrict__ out, int N) {
  constexpr int CG = COLS / 8;
  constexpr int RT = 256 / CG;
  constexpr int ROWS = RT * RPT;
  __shared__ float xs[ROWS][132];
  int tid = threadIdx.x;
  int row0 = blockIdx.x * ROWS;
  for (int i = tid; i < ROWS * 32; i += 256) {
    int r = i >> 5, c4 = (i & 31) << 2;
    float4 v = make_float4(0.f, 0.f, 0.f, 0.f);
    int gr = row0 + r;
    if (gr < N) v = *(const float4*)&A[(size_t)gr * 128 + c4];
    *(float4*)&xs[r][c4] = v;
  }
  __syncthreads();
  int cg = tid % CG;
  int rt = tid / CG;
  float acc[RPT][8];
#pragma unroll
  for (int rr = 0; rr < RPT; rr++)
#pragma unroll
    for (int c = 0; c < 8; c++) acc[rr][c] = 0.f;
  const float* wp = W + cg * 8;
  for (int k = 0; k < 128; k++) {
    float4 w0 = *(const float4*)&wp[k * COLS];
    float4 w1 = *(const float4*)&wp[k * COLS + 4];
#pragma unroll
    for (int rr = 0; rr < RPT; rr++) {
      float a = xs[rt * RPT + rr][k];
      acc[rr][0] = fmaf(a, w0.x, acc[rr][0]);
      acc[rr][1] = fmaf(a, w0.y, acc[rr][1]);
      acc[rr][2] = fmaf(a, w0.z, acc[rr][2]);
      acc[rr][3] = fmaf(a, w0.w, acc[rr][3]);
      acc[rr][4] = fmaf(a, w1.x, acc[rr][4]);
      acc[rr][5] = fmaf(a, w1.y, acc[rr][5]);
      acc[rr][6] = fmaf(a, w1.z, acc[rr][6]);
      acc[rr][7] = fmaf(a, w1.w, acc[rr][7]);
    }
  }
#pragma unroll
  for (int rr = 0; rr < RPT; rr++) {
    int gr = row0 + rt * RPT + rr;
    if (gr < N) {
      float4* o = (float4*)&out[(size_t)gr * COLS + cg * 8];
      o[0] = make_float4(acc[rr][0], acc[rr][1], acc[rr][2], acc[rr][3]);
      o[1] = make_float4(acc[rr][4], acc[rr][5], acc[rr][6], acc[rr][7]);
    }
  }
}

// ---- Aggregation (pull) + bias + ReLU + LayerNorm, 128 dims --------------
// One wave per node; lane owns dims {2l, 2l+1}. norm factored:
// out[i] = dinv[i] * (sum_e dinv[s]*xw[s] + dinv[i]*xw[i])

__global__ __launch_bounds__(256) void k_agg_ln(
    const float* __restrict__ xw, const int* __restrict__ csr,
    const int* __restrict__ row_start, const int* __restrict__ deg,
    const float* __restrict__ dinv, const float* __restrict__ b,
    const float* __restrict__ g, const float* __restrict__ be,
    float* __restrict__ h, int N) {
  int node = blockIdx.x * 4 + (threadIdx.x >> 6);
  if (node >= N) return;
  int lane = threadIdx.x & 63;
  const float2* xw2 = (const float2*)xw;
  float di = dinv[node];
  float2 v = xw2[(size_t)node * 64 + lane];
  float ax = di * v.x, ay = di * v.y;
  int s0 = row_start[node];
  int cnt = deg[node];
  for (int j = 0; j < cnt; j++) {
    int s = csr[s0 + j];
    float ds = dinv[s];
    float2 u = xw2[(size_t)s * 64 + lane];
    ax = fmaf(ds, u.x, ax);
    ay = fmaf(ds, u.y, ay);
  }
  float2 bb = ((const float2*)b)[lane];
  ax = fmaf(ax, di, bb.x);
  ay = fmaf(ay, di, bb.y);
  ax = fmaxf(ax, 0.f);
  ay = fmaxf(ay, 0.f);
  float mean = wave_red(ax + ay) * (1.f / 128.f);
  float dx = ax - mean, dy = ay - mean;
  float var = wave_red(dx * dx + dy * dy) * (1.f / 128.f);
  float rstd = rsqrtf(var + EPSV);
  float2 gg = ((const float2*)g)[lane];
  float2 ee = ((const float2*)be)[lane];
  float2 o;
  o.x = dx * rstd * gg.x + ee.x;
  o.y = dy * rstd * gg.y + ee.y;
  ((float2*)h)[(size_t)node * 64 + lane] = o;
}

// ---- Final aggregation, 64 dims, + bias only ------------------------------

__global__ __launch_bounds__(256) void k_agg_out(
    const float* __restrict__ xw, const int* __restrict__ csr,
    const int* __restrict__ row_start, const int* __restrict__ deg,
    const float* __restrict__ dinv, const float* __restrict__ b,
    float* __restrict__ out, int N) {
  int node = blockIdx.x * 4 + (threadIdx.x >> 6);
  if (node >= N) return;
  int lane = threadIdx.x & 63;
  float di = dinv[node];
  float a = di * xw[(size_t)node * 64 + lane];
  int s0 = row_start[node];
  int cnt = deg[node];
  for (int j = 0; j < cnt; j++) {
    int s = csr[s0 + j];
    a = fmaf(dinv[s], xw[(size_t)s * 64 + lane], a);
  }
  out[(size_t)node * 64 + lane] = a * di + b[lane];
}

// ---- Launch ---------------------------------------------------------------

extern "C" void kernel_launch(void* const* d_in, const int* in_sizes, int n_in,
                              void* d_out, int out_size, void* d_ws, size_t ws_size,
                              hipStream_t stream) {
  const float* x = (const float*)d_in[0];
  const int* ei = (const int*)d_in[1];
  const float* W1 = (const float*)d_in[2];
  const float* b1 = (const float*)d_in[3];
  const float* W2 = (const float*)d_in[4];
  const float* b2 = (const float*)d_in[5];
  const float* W3 = (const float*)d_in[6];
  const float* b3 = (const float*)d_in[7];
  const float* g1 = (const float*)d_in[8];
  const float* be1 = (const float*)d_in[9];
  const float* g2 = (const float*)d_in[10];
  const float* be2 = (const float*)d_in[11];

  int N = in_sizes[0] / 128;
  int E = in_sizes[1] / 2;
  const int* srcs = ei;
  const int* dsts = ei + E;

  char* ws = (char*)d_ws;
  size_t off = 0;
  auto alloc = [&](size_t bytes) -> char* {
    char* p = ws + off;
    off = (off + bytes + 255) & ~(size_t)255;
    return p;
  };
  float* dinv = (float*)alloc((size_t)N * 4);
  int* deg = (int*)alloc((size_t)N * 4);
  int* row_start = (int*)alloc((size_t)N * 4);
  int* cursor = (int*)alloc((size_t)N * 4);
  int* csr = (int*)alloc((size_t)E * 4);
  float* xw = (float*)alloc((size_t)N * 128 * 4);
  float* h = (float*)alloc((size_t)N * 128 * 4);

  hipMemsetAsync(deg, 0, (size_t)N * sizeof(int), stream);
  int eb = (E + 255) / 256;
  k_count<<<eb, 256, 0, stream>>>(dsts, deg, E);
  k_scan<<<1, 1024, 0, stream>>>(deg, row_start, cursor, dinv, N);
  k_fill<<<eb, 256, 0, stream>>>(srcs, dsts, cursor, csr, E);

  int gb = (N + 63) / 64;   // both gemm variants tile 64 rows/block
  int nb = (N + 3) / 4;     // 4 waves (nodes) per block

  // Layer 1
  k_gemm<128, 4><<<gb, 256, 0, stream>>>(x, W1, xw, N);
  k_agg_ln<<<nb, 256, 0, stream>>>(xw, csr, row_start, deg, dinv, b1, g1, be1, h, N);
  // Layer 2
  k_gemm<128, 4><<<gb, 256, 0, stream>>>(h, W2, xw, N);
  k_agg_ln<<<nb, 256, 0, stream>>>(xw, csr, row_start, deg, dinv, b2, g2, be2, h, N);
  // Layer 3
  k_gemm<64, 2><<<gb, 256, 0, stream>>>(h, W3, xw, N);
  k_agg_out<<<nb, 256, 0, stream>>>(xw, csr, row_start, deg, dinv, b3, (float*)d_out, N);
}

// Round 2
// 559.054 us; speedup vs baseline: 1.2226x; 1.2226x over previous
//
#include <hip/hip_runtime.h>

#define EPSV 1e-5f

__device__ __forceinline__ float wave_red(float v) {
#pragma unroll
  for (int off = 32; off > 0; off >>= 1) v += __shfl_xor(v, off, 64);
  return v;
}

// ---- CSR build ------------------------------------------------------------

__global__ void k_count(const int* __restrict__ dst, int* __restrict__ deg, int E) {
  int e = blockIdx.x * blockDim.x + threadIdx.x;
  if (e < E) atomicAdd(&deg[dst[e]], 1);
}

// Hierarchical exclusive scan of deg[N] (N<=65536 -> <=256 partials).
// k_partial: per-block sums. k_scan_partials: 1-block exclusive scan of the
// partials. k_write: per-block local scan + offset, writes row_start/cursor
// and fuses dinv = rsqrt(deg+1).

__global__ __launch_bounds__(256) void k_partial(const int* __restrict__ deg,
                                                 int* __restrict__ partials, int N) {
  __shared__ int red[256];
  int i = blockIdx.x * 256 + threadIdx.x;
  red[threadIdx.x] = (i < N) ? deg[i] : 0;
  __syncthreads();
#pragma unroll
  for (int off = 128; off > 0; off >>= 1) {
    if (threadIdx.x < off) red[threadIdx.x] += red[threadIdx.x + off];
    __syncthreads();
  }
  if (threadIdx.x == 0) partials[blockIdx.x] = red[0];
}

__global__ __launch_bounds__(256) void k_scan_partials(int* __restrict__ partials, int nb) {
  __shared__ int s[256];
  int t = threadIdx.x;
  s[t] = (t < nb) ? partials[t] : 0;
  __syncthreads();
#pragma unroll
  for (int off = 1; off < 256; off <<= 1) {
    int v = (t >= off) ? s[t - off] : 0;
    __syncthreads();
    s[t] += v;
    __syncthreads();
  }
  if (t < nb) partials[t] = (t > 0) ? s[t - 1] : 0;  // exclusive
}

__global__ __launch_bounds__(256) void k_write(const int* __restrict__ deg,
                                               const int* __restrict__ partials,
                                               int* __restrict__ row_start,
                                               int* __restrict__ cursor,
                                               float* __restrict__ dinv, int N) {
  __shared__ int s[256];
  int t = threadIdx.x;
  int i = blockIdx.x * 256 + t;
  int d = (i < N) ? deg[i] : 0;
  s[t] = d;
  __syncthreads();
#pragma unroll
  for (int off = 1; off < 256; off <<= 1) {
    int v = (t >= off) ? s[t - off] : 0;
    __syncthreads();
    s[t] += v;
    __syncthreads();
  }
  if (i < N) {
    int excl = partials[blockIdx.x] + s[t] - d;  // inclusive - self
    row_start[i] = excl;
    cursor[i] = excl;
    // reference: deg includes the self-loop (+1); always > 0
    dinv[i] = rsqrtf((float)(d + 1));
  }
}

__global__ void k_fill(const int* __restrict__ src, const int* __restrict__ dst,
                       int* __restrict__ cursor, int* __restrict__ csr_src, int E) {
  int e = blockIdx.x * blockDim.x + threadIdx.x;
  if (e < E) {
    int d = dst[e];
    int pos = atomicAdd(&cursor[d], 1);
    csr_src[pos] = src[e];
  }
}

// ---- GEMM: [N x 128] @ [128 x COLS] --------------------------------------
// 256 threads; thread = (cg, rt): cg owns 8 cols, rt owns RPT rows.
// x tile staged in LDS (padded stride 132 to break bank conflicts; 132*4B is
// 16B-multiple so float4 LDS ops stay aligned). W read via L1/L2 (64KB,
// fully cache-resident across blocks).

template <int COLS, int RPT>
__global__ __launch_bounds__(256) void k_gemm(const float* __restrict__ A,
                                              const float* __restrict__ W,
                                              float* __restrict__ out, int N) {
  constexpr int CG = COLS / 8;
  constexpr int RT = 256 / CG;
  constexpr int ROWS = RT * RPT;
  __shared__ float xs[ROWS][132];
  int tid = threadIdx.x;
  int row0 = blockIdx.x * ROWS;
  for (int i = tid; i < ROWS * 32; i += 256) {
    int r = i >> 5, c4 = (i & 31) << 2;
    float4 v = make_float4(0.f, 0.f, 0.f, 0.f);
    int gr = row0 + r;
    if (gr < N) v = *(const float4*)&A[(size_t)gr * 128 + c4];
    *(float4*)&xs[r][c4] = v;
  }
  __syncthreads();
  int cg = tid % CG;
  int rt = tid / CG;
  float acc[RPT][8];
#pragma unroll
  for (int rr = 0; rr < RPT; rr++)
#pragma unroll
    for (int c = 0; c < 8; c++) acc[rr][c] = 0.f;
  const float* wp = W + cg * 8;
  for (int k = 0; k < 128; k++) {
    float4 w0 = *(const float4*)&wp[k * COLS];
    float4 w1 = *(const float4*)&wp[k * COLS + 4];
#pragma unroll
    for (int rr = 0; rr < RPT; rr++) {
      float a = xs[rt * RPT + rr][k];
      acc[rr][0] = fmaf(a, w0.x, acc[rr][0]);
      acc[rr][1] = fmaf(a, w0.y, acc[rr][1]);
      acc[rr][2] = fmaf(a, w0.z, acc[rr][2]);
      acc[rr][3] = fmaf(a, w0.w, acc[rr][3]);
      acc[rr][4] = fmaf(a, w1.x, acc[rr][4]);
      acc[rr][5] = fmaf(a, w1.y, acc[rr][5]);
      acc[rr][6] = fmaf(a, w1.z, acc[rr][6]);
      acc[rr][7] = fmaf(a, w1.w, acc[rr][7]);
    }
  }
#pragma unroll
  for (int rr = 0; rr < RPT; rr++) {
    int gr = row0 + rt * RPT + rr;
    if (gr < N) {
      float4* o = (float4*)&out[(size_t)gr * COLS + cg * 8];
      o[0] = make_float4(acc[rr][0], acc[rr][1], acc[rr][2], acc[rr][3]);
      o[1] = make_float4(acc[rr][4], acc[rr][5], acc[rr][6], acc[rr][7]);
    }
  }
}

// ---- Aggregation (pull) + bias + ReLU + LayerNorm, 128 dims --------------
// One wave per node; lane owns dims {2l, 2l+1}. norm factored:
// out[i] = dinv[i] * (sum_e dinv[s]*xw[s] + dinv[i]*xw[i])

__global__ __launch_bounds__(256) void k_agg_ln(
    const float* __restrict__ xw, const int* __restrict__ csr,
    const int* __restrict__ row_start, const int* __restrict__ deg,
    const float* __restrict__ dinv, const float* __restrict__ b,
    const float* __restrict__ g, const float* __restrict__ be,
    float* __restrict__ h, int N) {
  int node = blockIdx.x * 4 + (threadIdx.x >> 6);
  if (node >= N) return;
  int lane = threadIdx.x & 63;
  const float2* xw2 = (const float2*)xw;
  float di = dinv[node];
  float2 v = xw2[(size_t)node * 64 + lane];
  float ax = di * v.x, ay = di * v.y;
  int s0 = row_start[node];
  int cnt = deg[node];
  for (int j = 0; j < cnt; j++) {
    int s = csr[s0 + j];
    float ds = dinv[s];
    float2 u = xw2[(size_t)s * 64 + lane];
    ax = fmaf(ds, u.x, ax);
    ay = fmaf(ds, u.y, ay);
  }
  float2 bb = ((const float2*)b)[lane];
  ax = fmaf(ax, di, bb.x);
  ay = fmaf(ay, di, bb.y);
  ax = fmaxf(ax, 0.f);
  ay = fmaxf(ay, 0.f);
  float mean = wave_red(ax + ay) * (1.f / 128.f);
  float dx = ax - mean, dy = ay - mean;
  float var = wave_red(dx * dx + dy * dy) * (1.f / 128.f);
  float rstd = rsqrtf(var + EPSV);
  float2 gg = ((const float2*)g)[lane];
  float2 ee = ((const float2*)be)[lane];
  float2 o;
  o.x = dx * rstd * gg.x + ee.x;
  o.y = dy * rstd * gg.y + ee.y;
  ((float2*)h)[(size_t)node * 64 + lane] = o;
}

// ---- Final aggregation, 64 dims, + bias only ------------------------------

__global__ __launch_bounds__(256) void k_agg_out(
    const float* __restrict__ xw, const int* __restrict__ csr,
    const int* __restrict__ row_start, const int* __restrict__ deg,
    const float* __restrict__ dinv, const float* __restrict__ b,
    float* __restrict__ out, int N) {
  int node = blockIdx.x * 4 + (threadIdx.x >> 6);
  if (node >= N) return;
  int lane = threadIdx.x & 63;
  float di = dinv[node];
  float a = di * xw[(size_t)node * 64 + lane];
  int s0 = row_start[node];
  int cnt = deg[node];
  for (int j = 0; j < cnt; j++) {
    int s = csr[s0 + j];
    a = fmaf(dinv[s], xw[(size_t)s * 64 + lane], a);
  }
  out[(size_t)node * 64 + lane] = a * di + b[lane];
}

// ---- Launch ---------------------------------------------------------------

extern "C" void kernel_launch(void* const* d_in, const int* in_sizes, int n_in,
                              void* d_out, int out_size, void* d_ws, size_t ws_size,
                              hipStream_t stream) {
  const float* x = (const float*)d_in[0];
  const int* ei = (const int*)d_in[1];
  const float* W1 = (const float*)d_in[2];
  const float* b1 = (const float*)d_in[3];
  const float* W2 = (const float*)d_in[4];
  const float* b2 = (const float*)d_in[5];
  const float* W3 = (const float*)d_in[6];
  const float* b3 = (const float*)d_in[7];
  const float* g1 = (const float*)d_in[8];
  const float* be1 = (const float*)d_in[9];
  const float* g2 = (const float*)d_in[10];
  const float* be2 = (const float*)d_in[11];

  int N = in_sizes[0] / 128;
  int E = in_sizes[1] / 2;
  const int* srcs = ei;
  const int* dsts = ei + E;

  char* ws = (char*)d_ws;
  size_t off = 0;
  auto alloc = [&](size_t bytes) -> char* {
    char* p = ws + off;
    off = (off + bytes + 255) & ~(size_t)255;
    return p;
  };
  float* dinv = (float*)alloc((size_t)N * 4);
  int* deg = (int*)alloc((size_t)N * 4);
  int* row_start = (int*)alloc((size_t)N * 4);
  int* cursor = (int*)alloc((size_t)N * 4);
  int* partials = (int*)alloc(256 * 4);
  int* csr = (int*)alloc((size_t)E * 4);
  float* xw = (float*)alloc((size_t)N * 128 * 4);
  float* h = (float*)alloc((size_t)N * 128 * 4);

  hipMemsetAsync(deg, 0, (size_t)N * sizeof(int), stream);
  int eb = (E + 255) / 256;
  int sb = (N + 255) / 256;  // 196 blocks for N=50000 (fits the 256-wide pass-2 scan)
  k_count<<<eb, 256, 0, stream>>>(dsts, deg, E);
  k_partial<<<sb, 256, 0, stream>>>(deg, partials, N);
  k_scan_partials<<<1, 256, 0, stream>>>(partials, sb);
  k_write<<<sb, 256, 0, stream>>>(deg, partials, row_start, cursor, dinv, N);
  k_fill<<<eb, 256, 0, stream>>>(srcs, dsts, cursor, csr, E);

  int gb = (N + 63) / 64;   // both gemm variants tile 64 rows/block
  int nb = (N + 3) / 4;     // 4 waves (nodes) per block

  // Layer 1
  k_gemm<128, 4><<<gb, 256, 0, stream>>>(x, W1, xw, N);
  k_agg_ln<<<nb, 256, 0, stream>>>(xw, csr, row_start, deg, dinv, b1, g1, be1, h, N);
  // Layer 2
  k_gemm<128, 4><<<gb, 256, 0, stream>>>(h, W2, xw, N);
  k_agg_ln<<<nb, 256, 0, stream>>>(xw, csr, row_start, deg, dinv, b2, g2, be2, h, N);
  // Layer 3
  k_gemm<64, 2><<<gb, 256, 0, stream>>>(h, W3, xw, N);
  k_agg_out<<<nb, 256, 0, stream>>>(xw, csr, row_start, deg, dinv, b3, (float*)d_out, N);
}

// Round 3
// 448.704 us; speedup vs baseline: 1.5232x; 1.2459x over previous
//
#include <hip/hip_runtime.h>

#define EPSV 1e-5f

typedef _Float16 half2_t __attribute__((ext_vector_type(2)));
typedef _Float16 half8_t __attribute__((ext_vector_type(8)));

__device__ __forceinline__ float wave_red(float v) {
#pragma unroll
  for (int off = 32; off > 0; off >>= 1) v += __shfl_xor(v, off, 64);
  return v;
}

// ---- CSR build ------------------------------------------------------------

__global__ void k_count(const int* __restrict__ dst, int* __restrict__ deg, int E) {
  int e = blockIdx.x * blockDim.x + threadIdx.x;
  if (e < E) atomicAdd(&deg[dst[e]], 1);
}

__global__ __launch_bounds__(256) void k_partial(const int* __restrict__ deg,
                                                 int* __restrict__ partials, int N) {
  __shared__ int red[256];
  int i = blockIdx.x * 256 + threadIdx.x;
  red[threadIdx.x] = (i < N) ? deg[i] : 0;
  __syncthreads();
#pragma unroll
  for (int off = 128; off > 0; off >>= 1) {
    if (threadIdx.x < off) red[threadIdx.x] += red[threadIdx.x + off];
    __syncthreads();
  }
  if (threadIdx.x == 0) partials[blockIdx.x] = red[0];
}

__global__ __launch_bounds__(256) void k_scan_partials(int* __restrict__ partials, int nb) {
  __shared__ int s[256];
  int t = threadIdx.x;
  s[t] = (t < nb) ? partials[t] : 0;
  __syncthreads();
#pragma unroll
  for (int off = 1; off < 256; off <<= 1) {
    int v = (t >= off) ? s[t - off] : 0;
    __syncthreads();
    s[t] += v;
    __syncthreads();
  }
  if (t < nb) partials[t] = (t > 0) ? s[t - 1] : 0;  // exclusive
}

__global__ __launch_bounds__(256) void k_write(const int* __restrict__ deg,
                                               const int* __restrict__ partials,
                                               int* __restrict__ row_start,
                                               int* __restrict__ cursor,
                                               float* __restrict__ dinv, int N) {
  __shared__ int s[256];
  int t = threadIdx.x;
  int i = blockIdx.x * 256 + t;
  int d = (i < N) ? deg[i] : 0;
  s[t] = d;
  __syncthreads();
#pragma unroll
  for (int off = 1; off < 256; off <<= 1) {
    int v = (t >= off) ? s[t - off] : 0;
    __syncthreads();
    s[t] += v;
    __syncthreads();
  }
  if (i < N) {
    int excl = partials[blockIdx.x] + s[t] - d;  // inclusive - self
    row_start[i] = excl;
    cursor[i] = excl;
    // reference: deg includes the self-loop (+1); always > 0
    dinv[i] = rsqrtf((float)(d + 1));
  }
}

__global__ void k_fill(const int* __restrict__ src, const int* __restrict__ dst,
                       int* __restrict__ cursor, int* __restrict__ csr_src, int E) {
  int e = blockIdx.x * blockDim.x + threadIdx.x;
  if (e < E) {
    int d = dst[e];
    int pos = atomicAdd(&cursor[d], 1);
    csr_src[pos] = src[e];
  }
}

// ---- GEMM: [N x 128] fp32 @ [128 x COLS] fp32 -> fp16 out -----------------
// 256 threads; thread = (cg, rt): cg owns 8 cols, rt owns RPT rows.
// fp32 accumulate, fp16 store (xw is consumed only by the gather kernels;
// halving its row size halves the XCD-replicated L2 fill traffic).

template <int COLS, int RPT>
__global__ __launch_bounds__(256) void k_gemm(const float* __restrict__ A,
                                              const float* __restrict__ W,
                                              _Float16* __restrict__ out, int N) {
  constexpr int CG = COLS / 8;
  constexpr int RT = 256 / CG;
  constexpr int ROWS = RT * RPT;
  __shared__ float xs[ROWS][132];
  int tid = threadIdx.x;
  int row0 = blockIdx.x * ROWS;
  for (int i = tid; i < ROWS * 32; i += 256) {
    int r = i >> 5, c4 = (i & 31) << 2;
    float4 v = make_float4(0.f, 0.f, 0.f, 0.f);
    int gr = row0 + r;
    if (gr < N) v = *(const float4*)&A[(size_t)gr * 128 + c4];
    *(float4*)&xs[r][c4] = v;
  }
  __syncthreads();
  int cg = tid % CG;
  int rt = tid / CG;
  float acc[RPT][8];
#pragma unroll
  for (int rr = 0; rr < RPT; rr++)
#pragma unroll
    for (int c = 0; c < 8; c++) acc[rr][c] = 0.f;
  const float* wp = W + cg * 8;
  for (int k = 0; k < 128; k++) {
    float4 w0 = *(const float4*)&wp[k * COLS];
    float4 w1 = *(const float4*)&wp[k * COLS + 4];
#pragma unroll
    for (int rr = 0; rr < RPT; rr++) {
      float a = xs[rt * RPT + rr][k];
      acc[rr][0] = fmaf(a, w0.x, acc[rr][0]);
      acc[rr][1] = fmaf(a, w0.y, acc[rr][1]);
      acc[rr][2] = fmaf(a, w0.z, acc[rr][2]);
      acc[rr][3] = fmaf(a, w0.w, acc[rr][3]);
      acc[rr][4] = fmaf(a, w1.x, acc[rr][4]);
      acc[rr][5] = fmaf(a, w1.y, acc[rr][5]);
      acc[rr][6] = fmaf(a, w1.z, acc[rr][6]);
      acc[rr][7] = fmaf(a, w1.w, acc[rr][7]);
    }
  }
#pragma unroll
  for (int rr = 0; rr < RPT; rr++) {
    int gr = row0 + rt * RPT + rr;
    if (gr < N) {
      half8_t o;
#pragma unroll
      for (int c = 0; c < 8; c++) o[c] = (_Float16)acc[rr][c];
      *(half8_t*)&out[(size_t)gr * COLS + cg * 8] = o;
    }
  }
}

// ---- Aggregation (pull) + bias + ReLU + LayerNorm, 128 dims ---------------
// One wave per node; lane owns dims {2l, 2l+1}. norm factored:
// out[i] = dinv[i] * (sum_e dinv[s]*xw[s] + dinv[i]*xw[i])
// xw is fp16 (half the gather traffic); accumulate fp32; 2-way unroll with
// split accumulators to break the FMA dependence chain.

__global__ __launch_bounds__(256) void k_agg_ln(
    const _Float16* __restrict__ xw, const int* __restrict__ csr,
    const int* __restrict__ row_start, const int* __restrict__ deg,
    const float* __restrict__ dinv, const float* __restrict__ b,
    const float* __restrict__ g, const float* __restrict__ be,
    float* __restrict__ h, int N) {
  int node = blockIdx.x * 4 + (threadIdx.x >> 6);
  if (node >= N) return;
  int lane = threadIdx.x & 63;
  const half2_t* xw2 = (const half2_t*)xw;
  float di = dinv[node];
  half2_t v = xw2[(size_t)node * 64 + lane];
  float ax0 = di * (float)v[0], ay0 = di * (float)v[1];
  float ax1 = 0.f, ay1 = 0.f;
  int s0 = row_start[node];
  int cnt = deg[node];
  int j = 0;
  for (; j + 2 <= cnt; j += 2) {
    int sA = csr[s0 + j];
    int sB = csr[s0 + j + 1];
    float dA = dinv[sA];
    float dB = dinv[sB];
    half2_t uA = xw2[(size_t)sA * 64 + lane];
    half2_t uB = xw2[(size_t)sB * 64 + lane];
    ax0 = fmaf(dA, (float)uA[0], ax0);
    ay0 = fmaf(dA, (float)uA[1], ay0);
    ax1 = fmaf(dB, (float)uB[0], ax1);
    ay1 = fmaf(dB, (float)uB[1], ay1);
  }
  if (j < cnt) {
    int s = csr[s0 + j];
    float ds = dinv[s];
    half2_t u = xw2[(size_t)s * 64 + lane];
    ax0 = fmaf(ds, (float)u[0], ax0);
    ay0 = fmaf(ds, (float)u[1], ay0);
  }
  float ax = ax0 + ax1, ay = ay0 + ay1;
  float2 bb = ((const float2*)b)[lane];
  ax = fmaf(ax, di, bb.x);
  ay = fmaf(ay, di, bb.y);
  ax = fmaxf(ax, 0.f);
  ay = fmaxf(ay, 0.f);
  float mean = wave_red(ax + ay) * (1.f / 128.f);
  float dx = ax - mean, dy = ay - mean;
  float var = wave_red(dx * dx + dy * dy) * (1.f / 128.f);
  float rstd = rsqrtf(var + EPSV);
  float2 gg = ((const float2*)g)[lane];
  float2 ee = ((const float2*)be)[lane];
  float2 o;
  o.x = dx * rstd * gg.x + ee.x;
  o.y = dy * rstd * gg.y + ee.y;
  ((float2*)h)[(size_t)node * 64 + lane] = o;
}

// ---- Final aggregation, 64 dims, + bias only ------------------------------

__global__ __launch_bounds__(256) void k_agg_out(
    const _Float16* __restrict__ xw, const int* __restrict__ csr,
    const int* __restrict__ row_start, const int* __restrict__ deg,
    const float* __restrict__ dinv, const float* __restrict__ b,
    float* __restrict__ out, int N) {
  int node = blockIdx.x * 4 + (threadIdx.x >> 6);
  if (node >= N) return;
  int lane = threadIdx.x & 63;
  float di = dinv[node];
  float a0 = di * (float)xw[(size_t)node * 64 + lane];
  float a1 = 0.f;
  int s0 = row_start[node];
  int cnt = deg[node];
  int j = 0;
  for (; j + 2 <= cnt; j += 2) {
    int sA = csr[s0 + j];
    int sB = csr[s0 + j + 1];
    a0 = fmaf(dinv[sA], (float)xw[(size_t)sA * 64 + lane], a0);
    a1 = fmaf(dinv[sB], (float)xw[(size_t)sB * 64 + lane], a1);
  }
  if (j < cnt) {
    int s = csr[s0 + j];
    a0 = fmaf(dinv[s], (float)xw[(size_t)s * 64 + lane], a0);
  }
  out[(size_t)node * 64 + lane] = (a0 + a1) * di + b[lane];
}

// ---- Launch ---------------------------------------------------------------

extern "C" void kernel_launch(void* const* d_in, const int* in_sizes, int n_in,
                              void* d_out, int out_size, void* d_ws, size_t ws_size,
                              hipStream_t stream) {
  const float* x = (const float*)d_in[0];
  const int* ei = (const int*)d_in[1];
  const float* W1 = (const float*)d_in[2];
  const float* b1 = (const float*)d_in[3];
  const float* W2 = (const float*)d_in[4];
  const float* b2 = (const float*)d_in[5];
  const float* W3 = (const float*)d_in[6];
  const float* b3 = (const float*)d_in[7];
  const float* g1 = (const float*)d_in[8];
  const float* be1 = (const float*)d_in[9];
  const float* g2 = (const float*)d_in[10];
  const float* be2 = (const float*)d_in[11];

  int N = in_sizes[0] / 128;
  int E = in_sizes[1] / 2;
  const int* srcs = ei;
  const int* dsts = ei + E;

  char* ws = (char*)d_ws;
  size_t off = 0;
  auto alloc = [&](size_t bytes) -> char* {
    char* p = ws + off;
    off = (off + bytes + 255) & ~(size_t)255;
    return p;
  };
  float* dinv = (float*)alloc((size_t)N * 4);
  int* deg = (int*)alloc((size_t)N * 4);
  int* row_start = (int*)alloc((size_t)N * 4);
  int* cursor = (int*)alloc((size_t)N * 4);
  int* partials = (int*)alloc(256 * 4);
  int* csr = (int*)alloc((size_t)E * 4);
  _Float16* xw = (_Float16*)alloc((size_t)N * 128 * 2);
  float* h = (float*)alloc((size_t)N * 128 * 4);

  hipMemsetAsync(deg, 0, (size_t)N * sizeof(int), stream);
  int eb = (E + 255) / 256;
  int sb = (N + 255) / 256;  // 196 blocks for N=50000 (fits the 256-wide pass-2 scan)
  k_count<<<eb, 256, 0, stream>>>(dsts, deg, E);
  k_partial<<<sb, 256, 0, stream>>>(deg, partials, N);
  k_scan_partials<<<1, 256, 0, stream>>>(partials, sb);
  k_write<<<sb, 256, 0, stream>>>(deg, partials, row_start, cursor, dinv, N);
  k_fill<<<eb, 256, 0, stream>>>(srcs, dsts, cursor, csr, E);

  int gb = (N + 63) / 64;   // both gemm variants tile 64 rows/block
  int nb = (N + 3) / 4;     // 4 waves (nodes) per block

  // Layer 1
  k_gemm<128, 4><<<gb, 256, 0, stream>>>(x, W1, xw, N);
  k_agg_ln<<<nb, 256, 0, stream>>>(xw, csr, row_start, deg, dinv, b1, g1, be1, h, N);
  // Layer 2
  k_gemm<128, 4><<<gb, 256, 0, stream>>>(h, W2, xw, N);
  k_agg_ln<<<nb, 256, 0, stream>>>(xw, csr, row_start, deg, dinv, b2, g2, be2, h, N);
  // Layer 3
  k_gemm<64, 2><<<gb, 256, 0, stream>>>(h, W3, xw, N);
  k_agg_out<<<nb, 256, 0, stream>>>(xw, csr, row_start, deg, dinv, b3, (float*)d_out, N);
}

// Round 4
// 387.209 us; speedup vs baseline: 1.7652x; 1.1588x over previous
//
#include <hip/hip_runtime.h>

#define EPSV 1e-5f

typedef _Float16 half2_t __attribute__((ext_vector_type(2)));
typedef _Float16 half8_t __attribute__((ext_vector_type(8)));

__device__ __forceinline__ float wave_red(float v) {
#pragma unroll
  for (int off = 32; off > 0; off >>= 1) v += __shfl_xor(v, off, 64);
  return v;
}

// ---- CSR build ------------------------------------------------------------

__global__ void k_count(const int* __restrict__ dst, int* __restrict__ deg, int E) {
  int e = blockIdx.x * blockDim.x + threadIdx.x;
  if (e < E) atomicAdd(&deg[dst[e]], 1);
}

__global__ __launch_bounds__(256) void k_partial(const int* __restrict__ deg,
                                                 int* __restrict__ partials, int N) {
  __shared__ int red[256];
  int i = blockIdx.x * 256 + threadIdx.x;
  red[threadIdx.x] = (i < N) ? deg[i] : 0;
  __syncthreads();
#pragma unroll
  for (int off = 128; off > 0; off >>= 1) {
    if (threadIdx.x < off) red[threadIdx.x] += red[threadIdx.x + off];
    __syncthreads();
  }
  if (threadIdx.x == 0) partials[blockIdx.x] = red[0];
}

__global__ __launch_bounds__(256) void k_scan_partials(int* __restrict__ partials, int nb) {
  __shared__ int s[256];
  int t = threadIdx.x;
  s[t] = (t < nb) ? partials[t] : 0;
  __syncthreads();
#pragma unroll
  for (int off = 1; off < 256; off <<= 1) {
    int v = (t >= off) ? s[t - off] : 0;
    __syncthreads();
    s[t] += v;
    __syncthreads();
  }
  if (t < nb) partials[t] = (t > 0) ? s[t - 1] : 0;  // exclusive
}

__global__ __launch_bounds__(256) void k_write(const int* __restrict__ deg,
                                               const int* __restrict__ partials,
                                               int* __restrict__ row_start,
                                               int* __restrict__ cursor,
                                               float* __restrict__ dinv, int N) {
  __shared__ int s[256];
  int t = threadIdx.x;
  int i = blockIdx.x * 256 + t;
  int d = (i < N) ? deg[i] : 0;
  s[t] = d;
  __syncthreads();
#pragma unroll
  for (int off = 1; off < 256; off <<= 1) {
    int v = (t >= off) ? s[t - off] : 0;
    __syncthreads();
    s[t] += v;
    __syncthreads();
  }
  if (i < N) {
    int excl = partials[blockIdx.x] + s[t] - d;  // inclusive - self
    row_start[i] = excl;
    cursor[i] = excl;
    // reference: deg includes the self-loop (+1); always > 0
    dinv[i] = rsqrtf((float)(d + 1));
  }
}

__global__ void k_fill(const int* __restrict__ src, const int* __restrict__ dst,
                       int* __restrict__ cursor, int* __restrict__ csr_src, int E) {
  int e = blockIdx.x * blockDim.x + threadIdx.x;
  if (e < E) {
    int d = dst[e];
    int pos = atomicAdd(&cursor[d], 1);
    csr_src[pos] = src[e];
  }
}

// ---- GEMM: [N x 128] fp32 @ [128 x COLS] fp32 -> fp16 y = dinv[row]*xw ----
// 256 threads; thread = (cg, rt): cg owns 8 cols, rt owns RPT rows.
// fp32 accumulate; epilogue pre-multiplies by dinv[row] so the aggregation
// needs no per-edge dinv gather; fp16 store halves gather traffic.

template <int COLS, int RPT>
__global__ __launch_bounds__(256) void k_gemm(const float* __restrict__ A,
                                              const float* __restrict__ W,
                                              const float* __restrict__ dinv,
                                              _Float16* __restrict__ out, int N) {
  constexpr int CG = COLS / 8;
  constexpr int RT = 256 / CG;
  constexpr int ROWS = RT * RPT;
  __shared__ float xs[ROWS][132];
  int tid = threadIdx.x;
  int row0 = blockIdx.x * ROWS;
  for (int i = tid; i < ROWS * 32; i += 256) {
    int r = i >> 5, c4 = (i & 31) << 2;
    float4 v = make_float4(0.f, 0.f, 0.f, 0.f);
    int gr = row0 + r;
    if (gr < N) v = *(const float4*)&A[(size_t)gr * 128 + c4];
    *(float4*)&xs[r][c4] = v;
  }
  __syncthreads();
  int cg = tid % CG;
  int rt = tid / CG;
  float acc[RPT][8];
#pragma unroll
  for (int rr = 0; rr < RPT; rr++)
#pragma unroll
    for (int c = 0; c < 8; c++) acc[rr][c] = 0.f;
  const float* wp = W + cg * 8;
  for (int k = 0; k < 128; k++) {
    float4 w0 = *(const float4*)&wp[k * COLS];
    float4 w1 = *(const float4*)&wp[k * COLS + 4];
#pragma unroll
    for (int rr = 0; rr < RPT; rr++) {
      float a = xs[rt * RPT + rr][k];
      acc[rr][0] = fmaf(a, w0.x, acc[rr][0]);
      acc[rr][1] = fmaf(a, w0.y, acc[rr][1]);
      acc[rr][2] = fmaf(a, w0.z, acc[rr][2]);
      acc[rr][3] = fmaf(a, w0.w, acc[rr][3]);
      acc[rr][4] = fmaf(a, w1.x, acc[rr][4]);
      acc[rr][5] = fmaf(a, w1.y, acc[rr][5]);
      acc[rr][6] = fmaf(a, w1.z, acc[rr][6]);
      acc[rr][7] = fmaf(a, w1.w, acc[rr][7]);
    }
  }
#pragma unroll
  for (int rr = 0; rr < RPT; rr++) {
    int gr = row0 + rt * RPT + rr;
    if (gr < N) {
      float dv = dinv[gr];
      half8_t o;
#pragma unroll
      for (int c = 0; c < 8; c++) o[c] = (_Float16)(acc[rr][c] * dv);
      *(half8_t*)&out[(size_t)gr * COLS + cg * 8] = o;
    }
  }
}

// ---- Aggregation (pull) + bias + ReLU + LayerNorm, 128 dims ---------------
// y holds dinv[r]*xw[r] (fp16). out[i] = dinv[i]*(sum_nbr y[s] + y[i]) + b.
// One wave per node; lane owns dims {2l,2l+1}. Up to 64 neighbor indices are
// fetched in ONE coalesced load (csr[s0+lane]) and broadcast via __shfl with
// a wave-uniform index -> v_readlane -> SGPR-based gather addresses; all y
// gathers are independent (no load->load chain).

__global__ __launch_bounds__(256) void k_agg_ln(
    const _Float16* __restrict__ y, const int* __restrict__ csr,
    const int* __restrict__ row_start, const int* __restrict__ deg,
    const float* __restrict__ dinv, const float* __restrict__ b,
    const float* __restrict__ g, const float* __restrict__ be,
    float* __restrict__ h, int N) {
  int node = blockIdx.x * 4 + (threadIdx.x >> 6);
  if (node >= N) return;
  int lane = threadIdx.x & 63;
  const half2_t* y2 = (const half2_t*)y;
  int s0 = row_start[node];
  int cnt = deg[node];
  int idx = 0;
  if (lane < cnt) idx = csr[s0 + lane];  // one load covers up to 64 edges
  half2_t v = y2[(size_t)node * 64 + lane];  // self term y[i]
  float ax0 = (float)v[0], ay0 = (float)v[1];
  float ax1 = 0.f, ay1 = 0.f;
  int m = min(cnt, 64);
  int j = 0;
  for (; j + 4 <= m; j += 4) {
    int sA = __shfl(idx, j, 64);
    int sB = __shfl(idx, j + 1, 64);
    int sC = __shfl(idx, j + 2, 64);
    int sD = __shfl(idx, j + 3, 64);
    half2_t uA = y2[(size_t)sA * 64 + lane];
    half2_t uB = y2[(size_t)sB * 64 + lane];
    half2_t uC = y2[(size_t)sC * 64 + lane];
    half2_t uD = y2[(size_t)sD * 64 + lane];
    ax0 += (float)uA[0]; ay0 += (float)uA[1];
    ax1 += (float)uB[0]; ay1 += (float)uB[1];
    ax0 += (float)uC[0]; ay0 += (float)uC[1];
    ax1 += (float)uD[0]; ay1 += (float)uD[1];
  }
  for (; j < m; j++) {
    int s = __shfl(idx, j, 64);
    half2_t u = y2[(size_t)s * 64 + lane];
    ax0 += (float)u[0]; ay0 += (float)u[1];
  }
  for (int k = 64; k < cnt; k++) {  // deg>64: essentially-never fallback
    int s = csr[s0 + k];
    half2_t u = y2[(size_t)s * 64 + lane];
    ax0 += (float)u[0]; ay0 += (float)u[1];
  }
  float di = dinv[node];
  float2 bb = ((const float2*)b)[lane];
  float ax = fmaf(ax0 + ax1, di, bb.x);
  float ay = fmaf(ay0 + ay1, di, bb.y);
  ax = fmaxf(ax, 0.f);
  ay = fmaxf(ay, 0.f);
  float mean = wave_red(ax + ay) * (1.f / 128.f);
  float dx = ax - mean, dy = ay - mean;
  float var = wave_red(dx * dx + dy * dy) * (1.f / 128.f);
  float rstd = rsqrtf(var + EPSV);
  float2 gg = ((const float2*)g)[lane];
  float2 ee = ((const float2*)be)[lane];
  float2 o;
  o.x = dx * rstd * gg.x + ee.x;
  o.y = dy * rstd * gg.y + ee.y;
  ((float2*)h)[(size_t)node * 64 + lane] = o;
}

// ---- Final aggregation, 64 dims, + bias only ------------------------------

__global__ __launch_bounds__(256) void k_agg_out(
    const _Float16* __restrict__ y, const int* __restrict__ csr,
    const int* __restrict__ row_start, const int* __restrict__ deg,
    const float* __restrict__ dinv, const float* __restrict__ b,
    float* __restrict__ out, int N) {
  int node = blockIdx.x * 4 + (threadIdx.x >> 6);
  if (node >= N) return;
  int lane = threadIdx.x & 63;
  int s0 = row_start[node];
  int cnt = deg[node];
  int idx = 0;
  if (lane < cnt) idx = csr[s0 + lane];
  float a0 = (float)y[(size_t)node * 64 + lane];  // self term
  float a1 = 0.f;
  int m = min(cnt, 64);
  int j = 0;
  for (; j + 4 <= m; j += 4) {
    int sA = __shfl(idx, j, 64);
    int sB = __shfl(idx, j + 1, 64);
    int sC = __shfl(idx, j + 2, 64);
    int sD = __shfl(idx, j + 3, 64);
    a0 += (float)y[(size_t)sA * 64 + lane];
    a1 += (float)y[(size_t)sB * 64 + lane];
    a0 += (float)y[(size_t)sC * 64 + lane];
    a1 += (float)y[(size_t)sD * 64 + lane];
  }
  for (; j < m; j++) {
    int s = __shfl(idx, j, 64);
    a0 += (float)y[(size_t)s * 64 + lane];
  }
  for (int k = 64; k < cnt; k++) {
    int s = csr[s0 + k];
    a0 += (float)y[(size_t)s * 64 + lane];
  }
  out[(size_t)node * 64 + lane] = (a0 + a1) * dinv[node] + b[lane];
}

// ---- Launch ---------------------------------------------------------------

extern "C" void kernel_launch(void* const* d_in, const int* in_sizes, int n_in,
                              void* d_out, int out_size, void* d_ws, size_t ws_size,
                              hipStream_t stream) {
  const float* x = (const float*)d_in[0];
  const int* ei = (const int*)d_in[1];
  const float* W1 = (const float*)d_in[2];
  const float* b1 = (const float*)d_in[3];
  const float* W2 = (const float*)d_in[4];
  const float* b2 = (const float*)d_in[5];
  const float* W3 = (const float*)d_in[6];
  const float* b3 = (const float*)d_in[7];
  const float* g1 = (const float*)d_in[8];
  const float* be1 = (const float*)d_in[9];
  const float* g2 = (const float*)d_in[10];
  const float* be2 = (const float*)d_in[11];

  int N = in_sizes[0] / 128;
  int E = in_sizes[1] / 2;
  const int* srcs = ei;
  const int* dsts = ei + E;

  char* ws = (char*)d_ws;
  size_t off = 0;
  auto alloc = [&](size_t bytes) -> char* {
    char* p = ws + off;
    off = (off + bytes + 255) & ~(size_t)255;
    return p;
  };
  float* dinv = (float*)alloc((size_t)N * 4);
  int* deg = (int*)alloc((size_t)N * 4);
  int* row_start = (int*)alloc((size_t)N * 4);
  int* cursor = (int*)alloc((size_t)N * 4);
  int* partials = (int*)alloc(256 * 4);
  int* csr = (int*)alloc((size_t)E * 4);
  _Float16* y = (_Float16*)alloc((size_t)N * 128 * 2);
  float* h = (float*)alloc((size_t)N * 128 * 4);

  hipMemsetAsync(deg, 0, (size_t)N * sizeof(int), stream);
  int eb = (E + 255) / 256;
  int sb = (N + 255) / 256;  // 196 blocks for N=50000 (fits the 256-wide pass-2 scan)
  k_count<<<eb, 256, 0, stream>>>(dsts, deg, E);
  k_partial<<<sb, 256, 0, stream>>>(deg, partials, N);
  k_scan_partials<<<1, 256, 0, stream>>>(partials, sb);
  k_write<<<sb, 256, 0, stream>>>(deg, partials, row_start, cursor, dinv, N);
  k_fill<<<eb, 256, 0, stream>>>(srcs, dsts, cursor, csr, E);

  int gb = (N + 63) / 64;   // both gemm variants tile 64 rows/block
  int nb = (N + 3) / 4;     // 4 waves (nodes) per block

  // Layer 1
  k_gemm<128, 4><<<gb, 256, 0, stream>>>(x, W1, dinv, y, N);
  k_agg_ln<<<nb, 256, 0, stream>>>(y, csr, row_start, deg, dinv, b1, g1, be1, h, N);
  // Layer 2
  k_gemm<128, 4><<<gb, 256, 0, stream>>>(h, W2, dinv, y, N);
  k_agg_ln<<<nb, 256, 0, stream>>>(y, csr, row_start, deg, dinv, b2, g2, be2, h, N);
  // Layer 3
  k_gemm<64, 2><<<gb, 256, 0, stream>>>(h, W3, dinv, y, N);
  k_agg_out<<<nb, 256, 0, stream>>>(y, csr, row_start, deg, dinv, b3, (float*)d_out, N);
}

// Round 5
// 381.539 us; speedup vs baseline: 1.7914x; 1.0149x over previous
//
#include <hip/hip_runtime.h>

#define EPSV 1e-5f

typedef _Float16 half2_t __attribute__((ext_vector_type(2)));
typedef _Float16 half8_t __attribute__((ext_vector_type(8)));

__device__ __forceinline__ float wave_red(float v) {
#pragma unroll
  for (int off = 32; off > 0; off >>= 1) v += __shfl_xor(v, off, 64);
  return v;
}

// ---- CSR build ------------------------------------------------------------
// Both k_count and k_fill are XCD-sliced: blockIdx&7 ~ XCD id (round-robin
// heuristic, perf-only). Slice s handles only dst in [N*s/8, N*(s+1)/8), so
// each XCD's random writes/atomics land in a ~400KB L2-resident region
// (kills the 64B-line write amplification: 52MB -> ~4MB HBM writes). All
// slices stream the whole edge list; the shared L3 absorbs the 8x re-read.
// Edge reads are non-temporal so streaming doesn't evict the dirty csr lines.

__global__ __launch_bounds__(256) void k_count(const int* __restrict__ dst,
                                               int* __restrict__ deg, int E, int N) {
  int slice = blockIdx.x & 7;
  int lo = (int)(((long long)N * slice) >> 3);
  int hi = (int)(((long long)N * (slice + 1)) >> 3);
  int r = (blockIdx.x >> 3) * blockDim.x + threadIdx.x;
  int stride = (gridDim.x >> 3) * blockDim.x;
  for (int e = r; e < E; e += stride) {
    int d = __builtin_nontemporal_load(&dst[e]);
    if (d >= lo && d < hi) atomicAdd(&deg[d], 1);
  }
}

__global__ __launch_bounds__(256) void k_fill(const int* __restrict__ src,
                                              const int* __restrict__ dst,
                                              int* __restrict__ cursor,
                                              int* __restrict__ csr_src, int E, int N) {
  int slice = blockIdx.x & 7;
  int lo = (int)(((long long)N * slice) >> 3);
  int hi = (int)(((long long)N * (slice + 1)) >> 3);
  int r = (blockIdx.x >> 3) * blockDim.x + threadIdx.x;
  int stride = (gridDim.x >> 3) * blockDim.x;
  for (int e = r; e < E; e += stride) {
    int d = __builtin_nontemporal_load(&dst[e]);
    if (d >= lo && d < hi) {
      int s = __builtin_nontemporal_load(&src[e]);
      int pos = atomicAdd(&cursor[d], 1);
      csr_src[pos] = s;
    }
  }
}

__global__ __launch_bounds__(256) void k_partial(const int* __restrict__ deg,
                                                 int* __restrict__ partials, int N) {
  __shared__ int red[256];
  int i = blockIdx.x * 256 + threadIdx.x;
  red[threadIdx.x] = (i < N) ? deg[i] : 0;
  __syncthreads();
#pragma unroll
  for (int off = 128; off > 0; off >>= 1) {
    if (threadIdx.x < off) red[threadIdx.x] += red[threadIdx.x + off];
    __syncthreads();
  }
  if (threadIdx.x == 0) partials[blockIdx.x] = red[0];
}

__global__ __launch_bounds__(256) void k_scan_partials(int* __restrict__ partials, int nb) {
  __shared__ int s[256];
  int t = threadIdx.x;
  s[t] = (t < nb) ? partials[t] : 0;
  __syncthreads();
#pragma unroll
  for (int off = 1; off < 256; off <<= 1) {
    int v = (t >= off) ? s[t - off] : 0;
    __syncthreads();
    s[t] += v;
    __syncthreads();
  }
  if (t < nb) partials[t] = (t > 0) ? s[t - 1] : 0;  // exclusive
}

__global__ __launch_bounds__(256) void k_write(const int* __restrict__ deg,
                                               const int* __restrict__ partials,
                                               int* __restrict__ row_start,
                                               int* __restrict__ cursor,
                                               float* __restrict__ dinv, int N) {
  __shared__ int s[256];
  int t = threadIdx.x;
  int i = blockIdx.x * 256 + t;
  int d = (i < N) ? deg[i] : 0;
  s[t] = d;
  __syncthreads();
#pragma unroll
  for (int off = 1; off < 256; off <<= 1) {
    int v = (t >= off) ? s[t - off] : 0;
    __syncthreads();
    s[t] += v;
    __syncthreads();
  }
  if (i < N) {
    int excl = partials[blockIdx.x] + s[t] - d;  // inclusive - self
    row_start[i] = excl;
    cursor[i] = excl;
    // reference: deg includes the self-loop (+1); always > 0
    dinv[i] = rsqrtf((float)(d + 1));
  }
}

// ---- GEMM: [N x 128] fp32 @ [128 x COLS] fp32 -> fp16 y = dinv[row]*xw ----
// 256 threads; thread = (cg, rt): cg owns 8 cols, rt owns RPT rows.
// fp32 accumulate; epilogue pre-multiplies by dinv[row] so the aggregation
// needs no per-edge dinv gather; fp16 store halves gather traffic.

template <int COLS, int RPT>
__global__ __launch_bounds__(256) void k_gemm(const float* __restrict__ A,
                                              const float* __restrict__ W,
                                              const float* __restrict__ dinv,
                                              _Float16* __restrict__ out, int N) {
  constexpr int CG = COLS / 8;
  constexpr int RT = 256 / CG;
  constexpr int ROWS = RT * RPT;
  __shared__ float xs[ROWS][132];
  int tid = threadIdx.x;
  int row0 = blockIdx.x * ROWS;
  for (int i = tid; i < ROWS * 32; i += 256) {
    int r = i >> 5, c4 = (i & 31) << 2;
    float4 v = make_float4(0.f, 0.f, 0.f, 0.f);
    int gr = row0 + r;
    if (gr < N) v = *(const float4*)&A[(size_t)gr * 128 + c4];
    *(float4*)&xs[r][c4] = v;
  }
  __syncthreads();
  int cg = tid % CG;
  int rt = tid / CG;
  float acc[RPT][8];
#pragma unroll
  for (int rr = 0; rr < RPT; rr++)
#pragma unroll
    for (int c = 0; c < 8; c++) acc[rr][c] = 0.f;
  const float* wp = W + cg * 8;
  for (int k = 0; k < 128; k++) {
    float4 w0 = *(const float4*)&wp[k * COLS];
    float4 w1 = *(const float4*)&wp[k * COLS + 4];
#pragma unroll
    for (int rr = 0; rr < RPT; rr++) {
      float a = xs[rt * RPT + rr][k];
      acc[rr][0] = fmaf(a, w0.x, acc[rr][0]);
      acc[rr][1] = fmaf(a, w0.y, acc[rr][1]);
      acc[rr][2] = fmaf(a, w0.z, acc[rr][2]);
      acc[rr][3] = fmaf(a, w0.w, acc[rr][3]);
      acc[rr][4] = fmaf(a, w1.x, acc[rr][4]);
      acc[rr][5] = fmaf(a, w1.y, acc[rr][5]);
      acc[rr][6] = fmaf(a, w1.z, acc[rr][6]);
      acc[rr][7] = fmaf(a, w1.w, acc[rr][7]);
    }
  }
#pragma unroll
  for (int rr = 0; rr < RPT; rr++) {
    int gr = row0 + rt * RPT + rr;
    if (gr < N) {
      float dv = dinv[gr];
      half8_t o;
#pragma unroll
      for (int c = 0; c < 8; c++) o[c] = (_Float16)(acc[rr][c] * dv);
      *(half8_t*)&out[(size_t)gr * COLS + cg * 8] = o;
    }
  }
}

// ---- Aggregation (pull) + bias + ReLU + LayerNorm, 128 dims ---------------
// y holds dinv[r]*xw[r] (fp16). out[i] = dinv[i]*(sum_nbr y[s] + y[i]) + b.
// One wave per node; lane owns dims {2l,2l+1}. Up to 64 neighbor indices are
// fetched in ONE coalesced load (csr[s0+lane]) and broadcast via __shfl with
// a wave-uniform index -> v_readlane -> SGPR-based gather addresses; all y
// gathers are independent (no load->load chain).

__global__ __launch_bounds__(256) void k_agg_ln(
    const _Float16* __restrict__ y, const int* __restrict__ csr,
    const int* __restrict__ row_start, const int* __restrict__ deg,
    const float* __restrict__ dinv, const float* __restrict__ b,
    const float* __restrict__ g, const float* __restrict__ be,
    float* __restrict__ h, int N) {
  int node = blockIdx.x * 4 + (threadIdx.x >> 6);
  if (node >= N) return;
  int lane = threadIdx.x & 63;
  const half2_t* y2 = (const half2_t*)y;
  int s0 = row_start[node];
  int cnt = deg[node];
  int idx = 0;
  if (lane < cnt) idx = csr[s0 + lane];  // one load covers up to 64 edges
  half2_t v = y2[(size_t)node * 64 + lane];  // self term y[i]
  float ax0 = (float)v[0], ay0 = (float)v[1];
  float ax1 = 0.f, ay1 = 0.f;
  int m = min(cnt, 64);
  int j = 0;
  for (; j + 4 <= m; j += 4) {
    int sA = __shfl(idx, j, 64);
    int sB = __shfl(idx, j + 1, 64);
    int sC = __shfl(idx, j + 2, 64);
    int sD = __shfl(idx, j + 3, 64);
    half2_t uA = y2[(size_t)sA * 64 + lane];
    half2_t uB = y2[(size_t)sB * 64 + lane];
    half2_t uC = y2[(size_t)sC * 64 + lane];
    half2_t uD = y2[(size_t)sD * 64 + lane];
    ax0 += (float)uA[0]; ay0 += (float)uA[1];
    ax1 += (float)uB[0]; ay1 += (float)uB[1];
    ax0 += (float)uC[0]; ay0 += (float)uC[1];
    ax1 += (float)uD[0]; ay1 += (float)uD[1];
  }
  for (; j < m; j++) {
    int s = __shfl(idx, j, 64);
    half2_t u = y2[(size_t)s * 64 + lane];
    ax0 += (float)u[0]; ay0 += (float)u[1];
  }
  for (int k = 64; k < cnt; k++) {  // deg>64: essentially-never fallback
    int s = csr[s0 + k];
    half2_t u = y2[(size_t)s * 64 + lane];
    ax0 += (float)u[0]; ay0 += (float)u[1];
  }
  float di = dinv[node];
  float2 bb = ((const float2*)b)[lane];
  float ax = fmaf(ax0 + ax1, di, bb.x);
  float ay = fmaf(ay0 + ay1, di, bb.y);
  ax = fmaxf(ax, 0.f);
  ay = fmaxf(ay, 0.f);
  float mean = wave_red(ax + ay) * (1.f / 128.f);
  float dx = ax - mean, dy = ay - mean;
  float var = wave_red(dx * dx + dy * dy) * (1.f / 128.f);
  float rstd = rsqrtf(var + EPSV);
  float2 gg = ((const float2*)g)[lane];
  float2 ee = ((const float2*)be)[lane];
  float2 o;
  o.x = dx * rstd * gg.x + ee.x;
  o.y = dy * rstd * gg.y + ee.y;
  ((float2*)h)[(size_t)node * 64 + lane] = o;
}

// ---- Final aggregation, 64 dims, + bias only ------------------------------

__global__ __launch_bounds__(256) void k_agg_out(
    const _Float16* __restrict__ y, const int* __restrict__ csr,
    const int* __restrict__ row_start, const int* __restrict__ deg,
    const float* __restrict__ dinv, const float* __restrict__ b,
    float* __restrict__ out, int N) {
  int node = blockIdx.x * 4 + (threadIdx.x >> 6);
  if (node >= N) return;
  int lane = threadIdx.x & 63;
  int s0 = row_start[node];
  int cnt = deg[node];
  int idx = 0;
  if (lane < cnt) idx = csr[s0 + lane];
  float a0 = (float)y[(size_t)node * 64 + lane];  // self term
  float a1 = 0.f;
  int m = min(cnt, 64);
  int j = 0;
  for (; j + 4 <= m; j += 4) {
    int sA = __shfl(idx, j, 64);
    int sB = __shfl(idx, j + 1, 64);
    int sC = __shfl(idx, j + 2, 64);
    int sD = __shfl(idx, j + 3, 64);
    a0 += (float)y[(size_t)sA * 64 + lane];
    a1 += (float)y[(size_t)sB * 64 + lane];
    a0 += (float)y[(size_t)sC * 64 + lane];
    a1 += (float)y[(size_t)sD * 64 + lane];
  }
  for (; j < m; j++) {
    int s = __shfl(idx, j, 64);
    a0 += (float)y[(size_t)s * 64 + lane];
  }
  for (int k = 64; k < cnt; k++) {
    int s = csr[s0 + k];
    a0 += (float)y[(size_t)s * 64 + lane];
  }
  out[(size_t)node * 64 + lane] = (a0 + a1) * dinv[node] + b[lane];
}

// ---- Launch ---------------------------------------------------------------

extern "C" void kernel_launch(void* const* d_in, const int* in_sizes, int n_in,
                              void* d_out, int out_size, void* d_ws, size_t ws_size,
                              hipStream_t stream) {
  const float* x = (const float*)d_in[0];
  const int* ei = (const int*)d_in[1];
  const float* W1 = (const float*)d_in[2];
  const float* b1 = (const float*)d_in[3];
  const float* W2 = (const float*)d_in[4];
  const float* b2 = (const float*)d_in[5];
  const float* W3 = (const float*)d_in[6];
  const float* b3 = (const float*)d_in[7];
  const float* g1 = (const float*)d_in[8];
  const float* be1 = (const float*)d_in[9];
  const float* g2 = (const float*)d_in[10];
  const float* be2 = (const float*)d_in[11];

  int N = in_sizes[0] / 128;
  int E = in_sizes[1] / 2;
  const int* srcs = ei;
  const int* dsts = ei + E;

  char* ws = (char*)d_ws;
  size_t off = 0;
  auto alloc = [&](size_t bytes) -> char* {
    char* p = ws + off;
    off = (off + bytes + 255) & ~(size_t)255;
    return p;
  };
  float* dinv = (float*)alloc((size_t)N * 4);
  int* deg = (int*)alloc((size_t)N * 4);
  int* row_start = (int*)alloc((size_t)N * 4);
  int* cursor = (int*)alloc((size_t)N * 4);
  int* partials = (int*)alloc(256 * 4);
  int* csr = (int*)alloc((size_t)E * 4);
  _Float16* y = (_Float16*)alloc((size_t)N * 128 * 2);
  float* h = (float*)alloc((size_t)N * 128 * 4);

  hipMemsetAsync(deg, 0, (size_t)N * sizeof(int), stream);
  int sb = (N + 255) / 256;  // 196 blocks for N=50000 (fits the 256-wide pass-2 scan)
  // 2048 blocks = 8 slices x 256 blocks; slice = blockIdx&7 ~ XCD
  k_count<<<2048, 256, 0, stream>>>(dsts, deg, E, N);
  k_partial<<<sb, 256, 0, stream>>>(deg, partials, N);
  k_scan_partials<<<1, 256, 0, stream>>>(partials, sb);
  k_write<<<sb, 256, 0, stream>>>(deg, partials, row_start, cursor, dinv, N);
  k_fill<<<2048, 256, 0, stream>>>(srcs, dsts, cursor, csr, E, N);

  int gb = (N + 63) / 64;   // both gemm variants tile 64 rows/block
  int nb = (N + 3) / 4;     // 4 waves (nodes) per block

  // Layer 1
  k_gemm<128, 4><<<gb, 256, 0, stream>>>(x, W1, dinv, y, N);
  k_agg_ln<<<nb, 256, 0, stream>>>(y, csr, row_start, deg, dinv, b1, g1, be1, h, N);
  // Layer 2
  k_gemm<128, 4><<<gb, 256, 0, stream>>>(h, W2, dinv, y, N);
  k_agg_ln<<<nb, 256, 0, stream>>>(y, csr, row_start, deg, dinv, b2, g2, be2, h, N);
  // Layer 3
  k_gemm<64, 2><<<gb, 256, 0, stream>>>(h, W3, dinv, y, N);
  k_agg_out<<<nb, 256, 0, stream>>>(y, csr, row_start, deg, dinv, b3, (float*)d_out, N);
}

// Round 6
// 312.374 us; speedup vs baseline: 2.1880x; 1.2214x over previous
//
#include <hip/hip_runtime.h>

#define EPSV 1e-5f

typedef _Float16 half2_t __attribute__((ext_vector_type(2)));
typedef _Float16 half8_t __attribute__((ext_vector_type(8)));
typedef float float4_t __attribute__((ext_vector_type(4)));

__device__ __forceinline__ float wave_red(float v) {
#pragma unroll
  for (int off = 32; off > 0; off >>= 1) v += __shfl_xor(v, off, 64);
  return v;
}

// ---- CSR build ------------------------------------------------------------
// k_count / k_fill XCD-sliced (blockIdx&7 ~ XCD): each XCD's random
// writes/atomics land in a ~400KB L2-resident region (kills 64B-line write
// amplification). All slices stream the whole edge list; L3 absorbs re-reads.

__global__ __launch_bounds__(256) void k_count(const int* __restrict__ dst,
                                               int* __restrict__ deg, int E, int N) {
  int slice = blockIdx.x & 7;
  int lo = (int)(((long long)N * slice) >> 3);
  int hi = (int)(((long long)N * (slice + 1)) >> 3);
  int r = (blockIdx.x >> 3) * blockDim.x + threadIdx.x;
  int stride = (gridDim.x >> 3) * blockDim.x;
  for (int e = r; e < E; e += stride) {
    int d = __builtin_nontemporal_load(&dst[e]);
    if (d >= lo && d < hi) atomicAdd(&deg[d], 1);
  }
}

__global__ __launch_bounds__(256) void k_fill(const int* __restrict__ src,
                                              const int* __restrict__ dst,
                                              int* __restrict__ cursor,
                                              int* __restrict__ csr_src, int E, int N) {
  int slice = blockIdx.x & 7;
  int lo = (int)(((long long)N * slice) >> 3);
  int hi = (int)(((long long)N * (slice + 1)) >> 3);
  int r = (blockIdx.x >> 3) * blockDim.x + threadIdx.x;
  int stride = (gridDim.x >> 3) * blockDim.x;
  for (int e = r; e < E; e += stride) {
    int d = __builtin_nontemporal_load(&dst[e]);
    if (d >= lo && d < hi) {
      int s = __builtin_nontemporal_load(&src[e]);
      int pos = atomicAdd(&cursor[d], 1);
      csr_src[pos] = s;
    }
  }
}

__global__ __launch_bounds__(256) void k_partial(const int* __restrict__ deg,
                                                 int* __restrict__ partials, int N) {
  __shared__ int red[256];
  int i = blockIdx.x * 256 + threadIdx.x;
  red[threadIdx.x] = (i < N) ? deg[i] : 0;
  __syncthreads();
#pragma unroll
  for (int off = 128; off > 0; off >>= 1) {
    if (threadIdx.x < off) red[threadIdx.x] += red[threadIdx.x + off];
    __syncthreads();
  }
  if (threadIdx.x == 0) partials[blockIdx.x] = red[0];
}

__global__ __launch_bounds__(256) void k_scan_partials(int* __restrict__ partials, int nb) {
  __shared__ int s[256];
  int t = threadIdx.x;
  s[t] = (t < nb) ? partials[t] : 0;
  __syncthreads();
#pragma unroll
  for (int off = 1; off < 256; off <<= 1) {
    int v = (t >= off) ? s[t - off] : 0;
    __syncthreads();
    s[t] += v;
    __syncthreads();
  }
  if (t < nb) partials[t] = (t > 0) ? s[t - 1] : 0;  // exclusive
}

__global__ __launch_bounds__(256) void k_write(const int* __restrict__ deg,
                                               const int* __restrict__ partials,
                                               int* __restrict__ row_start,
                                               int* __restrict__ cursor,
                                               float* __restrict__ dinv, int N) {
  __shared__ int s[256];
  int t = threadIdx.x;
  int i = blockIdx.x * 256 + t;
  int d = (i < N) ? deg[i] : 0;
  s[t] = d;
  __syncthreads();
#pragma unroll
  for (int off = 1; off < 256; off <<= 1) {
    int v = (t >= off) ? s[t - off] : 0;
    __syncthreads();
    s[t] += v;
    __syncthreads();
  }
  if (i < N) {
    int excl = partials[blockIdx.x] + s[t] - d;  // inclusive - self
    row_start[i] = excl;
    cursor[i] = excl;
    dinv[i] = rsqrtf((float)(d + 1));  // deg includes self-loop; > 0
  }
}

// ---- W pre-swizzle: fp32 [128 x COLS] -> fp16 B-fragment order ------------
// Wh[((nb*4+ks)*64 + lane)*8 + j] = W[ks*32 + (lane>>4)*8 + j][nb*16 + (lane&15)]
// so the GEMM's B loads are coalesced half8 reads in MFMA layout.

template <int COLS>
__global__ __launch_bounds__(256) void k_wprep(const float* __restrict__ W,
                                               _Float16* __restrict__ Wh) {
  constexpr int NT = (COLS / 16) * 4 * 64;
  int t = blockIdx.x * 256 + threadIdx.x;  // t = (nb*4+ks)*64 + lane
  if (t >= NT) return;
  int lane = t & 63;
  int ks = (t >> 6) & 3;
  int nb = t >> 8;
  int col = nb * 16 + (lane & 15);
  int k0 = ks * 32 + (lane >> 4) * 8;
  half8_t v;
#pragma unroll
  for (int j = 0; j < 8; j++) v[j] = (_Float16)W[(size_t)(k0 + j) * COLS + col];
  *(half8_t*)&Wh[(size_t)t * 8] = v;
}

// ---- GEMM via MFMA: [N x 128] fp32 -> fp16 y = dinv[row] * (A @ W) --------
// One wave per 16 rows x COLS. A-fragments loaded direct from global
// (A[m=lane&15][k=quad*8+j], cvt fp32->fp16); B from pre-swizzled Wh
// (L1/L2-resident); fp32 accumulate in MFMA; epilogue scales by dinv[row].
// D layout: row = quad*4 + reg, col = lane&15 (m89/m91-verified).

template <int COLS>
__global__ __launch_bounds__(256) void k_gemm_mfma(const float* __restrict__ A,
                                                   const _Float16* __restrict__ Wh,
                                                   const float* __restrict__ dinv,
                                                   _Float16* __restrict__ out, int N) {
  constexpr int NB = COLS / 16;
  int lane = threadIdx.x & 63;
  int w = threadIdx.x >> 6;
  int quad = lane >> 4;
  int mrow = blockIdx.x * 64 + w * 16 + (lane & 15);
  half8_t af[4];
  if (mrow < N) {
    const float* ap = A + (size_t)mrow * 128 + quad * 8;
#pragma unroll
    for (int ks = 0; ks < 4; ks++) {
      float4 f0 = *(const float4*)(ap + ks * 32);
      float4 f1 = *(const float4*)(ap + ks * 32 + 4);
      af[ks][0] = (_Float16)f0.x; af[ks][1] = (_Float16)f0.y;
      af[ks][2] = (_Float16)f0.z; af[ks][3] = (_Float16)f0.w;
      af[ks][4] = (_Float16)f1.x; af[ks][5] = (_Float16)f1.y;
      af[ks][6] = (_Float16)f1.z; af[ks][7] = (_Float16)f1.w;
    }
  } else {
#pragma unroll
    for (int ks = 0; ks < 4; ks++)
#pragma unroll
      for (int j = 0; j < 8; j++) af[ks][j] = (_Float16)0.f;
  }
  float4_t acc[NB];
#pragma unroll
  for (int nb = 0; nb < NB; nb++) acc[nb] = (float4_t){0.f, 0.f, 0.f, 0.f};
#pragma unroll
  for (int nb = 0; nb < NB; nb++) {
#pragma unroll
    for (int ks = 0; ks < 4; ks++) {
      half8_t bf = *(const half8_t*)&Wh[(size_t)((nb * 4 + ks) * 64 + lane) * 8];
      acc[nb] = __builtin_amdgcn_mfma_f32_16x16x32_f16(af[ks], bf, acc[nb], 0, 0, 0);
    }
  }
  int orow0 = blockIdx.x * 64 + w * 16 + quad * 4;
#pragma unroll
  for (int r = 0; r < 4; r++) {
    int row = orow0 + r;
    if (row < N) {
      float dv = dinv[row];
#pragma unroll
      for (int nb = 0; nb < NB; nb++)
        out[(size_t)row * COLS + nb * 16 + (lane & 15)] = (_Float16)(acc[nb][r] * dv);
    }
  }
}

// ---- Aggregation (pull) + bias + ReLU + LayerNorm, 128 dims ---------------
// y holds dinv[r]*xw[r] (fp16). out[i] = dinv[i]*(sum_nbr y[s] + y[i]) + b.
// Wave per node; 64 neighbor indices fetched in ONE coalesced load and
// broadcast via __shfl (wave-uniform j -> readlane -> SGPR gather base);
// all y gathers are independent (no load->load chain).

__global__ __launch_bounds__(256) void k_agg_ln(
    const _Float16* __restrict__ y, const int* __restrict__ csr,
    const int* __restrict__ row_start, const int* __restrict__ deg,
    const float* __restrict__ dinv, const float* __restrict__ b,
    const float* __restrict__ g, const float* __restrict__ be,
    float* __restrict__ h, int N) {
  int node = blockIdx.x * 4 + (threadIdx.x >> 6);
  if (node >= N) return;
  int lane = threadIdx.x & 63;
  const half2_t* y2 = (const half2_t*)y;
  int s0 = row_start[node];
  int cnt = deg[node];
  int idx = 0;
  if (lane < cnt) idx = csr[s0 + lane];
  half2_t v = y2[(size_t)node * 64 + lane];  // self term y[i]
  float ax0 = (float)v[0], ay0 = (float)v[1];
  float ax1 = 0.f, ay1 = 0.f;
  int m = min(cnt, 64);
  int j = 0;
  for (; j + 4 <= m; j += 4) {
    int sA = __shfl(idx, j, 64);
    int sB = __shfl(idx, j + 1, 64);
    int sC = __shfl(idx, j + 2, 64);
    int sD = __shfl(idx, j + 3, 64);
    half2_t uA = y2[(size_t)sA * 64 + lane];
    half2_t uB = y2[(size_t)sB * 64 + lane];
    half2_t uC = y2[(size_t)sC * 64 + lane];
    half2_t uD = y2[(size_t)sD * 64 + lane];
    ax0 += (float)uA[0]; ay0 += (float)uA[1];
    ax1 += (float)uB[0]; ay1 += (float)uB[1];
    ax0 += (float)uC[0]; ay0 += (float)uC[1];
    ax1 += (float)uD[0]; ay1 += (float)uD[1];
  }
  for (; j < m; j++) {
    int s = __shfl(idx, j, 64);
    half2_t u = y2[(size_t)s * 64 + lane];
    ax0 += (float)u[0]; ay0 += (float)u[1];
  }
  for (int k = 64; k < cnt; k++) {  // deg>64 fallback
    int s = csr[s0 + k];
    half2_t u = y2[(size_t)s * 64 + lane];
    ax0 += (float)u[0]; ay0 += (float)u[1];
  }
  float di = dinv[node];
  float2 bb = ((const float2*)b)[lane];
  float ax = fmaf(ax0 + ax1, di, bb.x);
  float ay = fmaf(ay0 + ay1, di, bb.y);
  ax = fmaxf(ax, 0.f);
  ay = fmaxf(ay, 0.f);
  float mean = wave_red(ax + ay) * (1.f / 128.f);
  float dx = ax - mean, dy = ay - mean;
  float var = wave_red(dx * dx + dy * dy) * (1.f / 128.f);
  float rstd = rsqrtf(var + EPSV);
  float2 gg = ((const float2*)g)[lane];
  float2 ee = ((const float2*)be)[lane];
  float2 o;
  o.x = dx * rstd * gg.x + ee.x;
  o.y = dy * rstd * gg.y + ee.y;
  ((float2*)h)[(size_t)node * 64 + lane] = o;
}

// ---- Final aggregation, 64 dims, + bias only ------------------------------

__global__ __launch_bounds__(256) void k_agg_out(
    const _Float16* __restrict__ y, const int* __restrict__ csr,
    const int* __restrict__ row_start, const int* __restrict__ deg,
    const float* __restrict__ dinv, const float* __restrict__ b,
    float* __restrict__ out, int N) {
  int node = blockIdx.x * 4 + (threadIdx.x >> 6);
  if (node >= N) return;
  int lane = threadIdx.x & 63;
  int s0 = row_start[node];
  int cnt = deg[node];
  int idx = 0;
  if (lane < cnt) idx = csr[s0 + lane];
  float a0 = (float)y[(size_t)node * 64 + lane];  // self term
  float a1 = 0.f;
  int m = min(cnt, 64);
  int j = 0;
  for (; j + 4 <= m; j += 4) {
    int sA = __shfl(idx, j, 64);
    int sB = __shfl(idx, j + 1, 64);
    int sC = __shfl(idx, j + 2, 64);
    int sD = __shfl(idx, j + 3, 64);
    a0 += (float)y[(size_t)sA * 64 + lane];
    a1 += (float)y[(size_t)sB * 64 + lane];
    a0 += (float)y[(size_t)sC * 64 + lane];
    a1 += (float)y[(size_t)sD * 64 + lane];
  }
  for (; j < m; j++) {
    int s = __shfl(idx, j, 64);
    a0 += (float)y[(size_t)s * 64 + lane];
  }
  for (int k = 64; k < cnt; k++) {
    int s = csr[s0 + k];
    a0 += (float)y[(size_t)s * 64 + lane];
  }
  out[(size_t)node * 64 + lane] = (a0 + a1) * dinv[node] + b[lane];
}

// ---- Launch ---------------------------------------------------------------

extern "C" void kernel_launch(void* const* d_in, const int* in_sizes, int n_in,
                              void* d_out, int out_size, void* d_ws, size_t ws_size,
                              hipStream_t stream) {
  const float* x = (const float*)d_in[0];
  const int* ei = (const int*)d_in[1];
  const float* W1 = (const float*)d_in[2];
  const float* b1 = (const float*)d_in[3];
  const float* W2 = (const float*)d_in[4];
  const float* b2 = (const float*)d_in[5];
  const float* W3 = (const float*)d_in[6];
  const float* b3 = (const float*)d_in[7];
  const float* g1 = (const float*)d_in[8];
  const float* be1 = (const float*)d_in[9];
  const float* g2 = (const float*)d_in[10];
  const float* be2 = (const float*)d_in[11];

  int N = in_sizes[0] / 128;
  int E = in_sizes[1] / 2;
  const int* srcs = ei;
  const int* dsts = ei + E;

  char* ws = (char*)d_ws;
  size_t off = 0;
  auto alloc = [&](size_t bytes) -> char* {
    char* p = ws + off;
    off = (off + bytes + 255) & ~(size_t)255;
    return p;
  };
  float* dinv = (float*)alloc((size_t)N * 4);
  int* deg = (int*)alloc((size_t)N * 4);
  int* row_start = (int*)alloc((size_t)N * 4);
  int* cursor = (int*)alloc((size_t)N * 4);
  int* partials = (int*)alloc(256 * 4);
  int* csr = (int*)alloc((size_t)E * 4);
  _Float16* y = (_Float16*)alloc((size_t)N * 128 * 2);
  float* h = (float*)alloc((size_t)N * 128 * 4);
  _Float16* Wh1 = (_Float16*)alloc(128 * 128 * 2);
  _Float16* Wh2 = (_Float16*)alloc(128 * 128 * 2);
  _Float16* Wh3 = (_Float16*)alloc(128 * 64 * 2);

  hipMemsetAsync(deg, 0, (size_t)N * sizeof(int), stream);
  int sb = (N + 255) / 256;
  // CSR build (XCD-sliced count/fill) + W pre-swizzles (independent work)
  k_count<<<2048, 256, 0, stream>>>(dsts, deg, E, N);
  k_wprep<128><<<8, 256, 0, stream>>>(W1, Wh1);
  k_wprep<128><<<8, 256, 0, stream>>>(W2, Wh2);
  k_wprep<64><<<4, 256, 0, stream>>>(W3, Wh3);
  k_partial<<<sb, 256, 0, stream>>>(deg, partials, N);
  k_scan_partials<<<1, 256, 0, stream>>>(partials, sb);
  k_write<<<sb, 256, 0, stream>>>(deg, partials, row_start, cursor, dinv, N);
  k_fill<<<2048, 256, 0, stream>>>(srcs, dsts, cursor, csr, E, N);

  int gb = (N + 63) / 64;  // 64 rows per block (4 waves x 16 rows)
  int nb = (N + 3) / 4;    // 4 waves (nodes) per block

  // Layer 1
  k_gemm_mfma<128><<<gb, 256, 0, stream>>>(x, Wh1, dinv, y, N);
  k_agg_ln<<<nb, 256, 0, stream>>>(y, csr, row_start, deg, dinv, b1, g1, be1, h, N);
  // Layer 2
  k_gemm_mfma<128><<<gb, 256, 0, stream>>>(h, Wh2, dinv, y, N);
  k_agg_ln<<<nb, 256, 0, stream>>>(y, csr, row_start, deg, dinv, b2, g2, be2, h, N);
  // Layer 3
  k_gemm_mfma<64><<<gb, 256, 0, stream>>>(h, Wh3, dinv, y, N);
  k_agg_out<<<nb, 256, 0, stream>>>(y, csr, row_start, deg, dinv, b3, (float*)d_out, N);
}